// Round 17
// baseline (222.084 us; speedup 1.0000x reference)
//
#include <hip/hip_runtime.h>
#include <hip/hip_bf16.h>

#define SEQT 2048
#define NH 16
#define HD 128

typedef __bf16 bf16;
typedef __bf16 bf16x4 __attribute__((ext_vector_type(4)));
typedef __bf16 bf16x8 __attribute__((ext_vector_type(8)));
typedef float f32x4 __attribute__((ext_vector_type(4)));
typedef float f32x16 __attribute__((ext_vector_type(16)));

__device__ inline void glds16(const bf16* g, bf16* l) {
  __builtin_amdgcn_global_load_lds(
      (const __attribute__((address_space(1))) unsigned int*)g,
      (__attribute__((address_space(3))) unsigned int*)l, 16, 0, 0);
}

__device__ inline unsigned int cvtpk(float a, float b) {
  unsigned int d;
  asm("v_cvt_pk_bf16_f32 %0, %1, %2" : "=v"(d) : "v"(a), "v"(b));
  return d;
}

// ---------- fp32 -> bf16 elementwise convert (8 elems/thread) ----------
__global__ __launch_bounds__(256) void k_convert(const float* __restrict__ in,
                                                 bf16* __restrict__ out, int n8) {
  int i = blockIdx.x * 256 + threadIdx.x;
  if (i >= n8) return;
  const float4* p = (const float4*)in + (size_t)i * 2;
  float4 a = p[0], b = p[1];
  bf16x8 o;
  o[0] = (bf16)a.x; o[1] = (bf16)a.y; o[2] = (bf16)a.z; o[3] = (bf16)a.w;
  o[4] = (bf16)b.x; o[5] = (bf16)b.y; o[6] = (bf16)b.z; o[7] = (bf16)b.w;
  *((bf16x8*)out + i) = o;
}

// ---------- transpose + convert: in (R x C) fp32 -> out (C x R) bf16 ----------
__global__ __launch_bounds__(256) void k_transpose(const float* __restrict__ in,
                                                   bf16* __restrict__ out, int R, int C) {
  __shared__ float tile[32][33];
  int c0 = blockIdx.x * 32, r0 = blockIdx.y * 32;
  int tx = threadIdx.x, ty = threadIdx.y;  // blockDim (32,8)
#pragma unroll
  for (int i = 0; i < 4; i++)
    tile[ty + i * 8][tx] = in[(size_t)(r0 + ty + i * 8) * C + c0 + tx];
  __syncthreads();
#pragma unroll
  for (int i = 0; i < 4; i++) {
    int r = ty + i * 8;
    out[(size_t)(c0 + r) * R + r0 + tx] = (bf16)tile[tx][r];
  }
}

// ---------- fused transpose of wq/wk/wv (and optionally wo) ----------
__global__ __launch_bounds__(256) void k_transpose3(const float* __restrict__ wq,
                                                    const float* __restrict__ wk,
                                                    const float* __restrict__ wv,
                                                    bf16* __restrict__ W) {
  __shared__ float tile[32][33];
  int bx = blockIdx.x;
  const float* src;
  bf16* dst;
  int C;
  if (bx < 64) {
    src = wq; dst = W; C = 2048;
  } else if (bx < 80) {
    src = wk; dst = W + 2048 * 2048; C = 512; bx -= 64;
  } else {
    src = wv; dst = W + 2560 * 2048; C = 512; bx -= 80;
  }
  int c0 = bx * 32, r0 = blockIdx.y * 32;
  int tx = threadIdx.x, ty = threadIdx.y;  // blockDim (32,8)
#pragma unroll
  for (int i = 0; i < 4; i++)
    tile[ty + i * 8][tx] = src[(size_t)(r0 + ty + i * 8) * C + c0 + tx];
  __syncthreads();
#pragma unroll
  for (int i = 0; i < 4; i++) {
    int r = ty + i * 8;
    dst[(size_t)(c0 + r) * 2048 + r0 + tx] = (bf16)tile[tx][r];
  }
}

__global__ __launch_bounds__(256) void k_transpose4(const float* __restrict__ wq,
                                                    const float* __restrict__ wk,
                                                    const float* __restrict__ wv,
                                                    const float* __restrict__ wo,
                                                    bf16* __restrict__ W,
                                                    bf16* __restrict__ WOT) {
  __shared__ float tile[32][33];
  int bx = blockIdx.x;
  const float* src;
  bf16* dst;
  int C;
  if (bx < 64) {
    src = wq; dst = W; C = 2048;
  } else if (bx < 80) {
    src = wk; dst = W + 2048 * 2048; C = 512; bx -= 64;
  } else if (bx < 96) {
    src = wv; dst = W + 2560 * 2048; C = 512; bx -= 80;
  } else {
    src = wo; dst = WOT; C = 2048; bx -= 96;
  }
  int c0 = bx * 32, r0 = blockIdx.y * 32;
  int tx = threadIdx.x, ty = threadIdx.y;  // blockDim (32,8)
#pragma unroll
  for (int i = 0; i < 4; i++)
    tile[ty + i * 8][tx] = src[(size_t)(r0 + ty + i * 8) * C + c0 + tx];
  __syncthreads();
#pragma unroll
  for (int i = 0; i < 4; i++) {
    int r = ty + i * 8;
    dst[(size_t)(c0 + r) * 2048 + r0 + tx] = (bf16)tile[tx][r];
  }
}

// ---------- 8-phase 256x256 bf16 GEMM (T3+T4 schedule, m201-style) ----------
// K-head RoPE fused into the epilogue: blocks with n0 in [2048,2560) apply
// rope to their output columns (pair exchange via shfl_xor(.,1): col parity
// == lr&1, partner col^1 lives in lane^1; dp=(col>>1)&63, t=row&2047).
template <typename OutT>
__global__ __launch_bounds__(512, 2) void k_gemm8(const bf16* __restrict__ A,
                                                  const bf16* __restrict__ Bt,
                                                  OutT* __restrict__ C,
                                                  int nbx, int K, int ldc,
                                                  const float* __restrict__ rc,
                                                  const float* __restrict__ rs) {
  __shared__ bf16 AB[2][2][16384];  // [buf][0=A,1=B][256 rows x 64 cols]
  int nb = gridDim.x;               // multiple of 8
  int cpx = nb >> 3;
  int bid = blockIdx.x;
  int sw = (bid & 7) * cpx + (bid >> 3);  // XCD-aware swizzle (bijective)
  int bx = sw % nbx, by = sw / nbx;
  int m0 = by << 8, n0 = bx << 8;
  int tid = threadIdx.x;
  int lane = tid & 63, wid = tid >> 6;
  int wr2 = wid >> 2, wc2 = wid & 3;
  int lr = lane & 15, lg = lane >> 4;
  int lx = lr & 7;

  f32x4 acc[2][4][2][2] = {};

  int srow = tid >> 3;
  int ssl8 = ((tid & 7) ^ (srow & 7)) * 8;  // pre-swizzled source col offset

#define STAGE(SBUF, SAB, SHALF, KO)                                           \
  {                                                                           \
    int ko = (KO) <= (K - 64) ? (KO) : 0;                                     \
    const bf16* gb = (SAB) ? Bt : A;                                          \
    int rb = ((SAB) ? n0 : m0) + (SHALF) * 128 + srow;                        \
    glds16(gb + (size_t)rb * K + ko + ssl8,                                   \
           &AB[SBUF][SAB][(SHALF) * 8192 + tid * 8]);                         \
    glds16(gb + (size_t)(rb + 64) * K + ko + ssl8,                            \
           &AB[SBUF][SAB][(SHALF) * 8192 + (512 + tid) * 8]);                 \
  }

#define PHASE(BUF, QM, QN, SBUF, SAB, SHALF, SKO, DOVM)                       \
  {                                                                           \
    bf16x8 af[4][2], bq[2][2];                                                \
    _Pragma("unroll") for (int mi = 0; mi < 4; mi++)                          \
      _Pragma("unroll") for (int kk = 0; kk < 2; kk++)                        \
        af[mi][kk] = *(const bf16x8*)&AB[BUF][0][                             \
            ((QM) * 128 + wr2 * 64 + mi * 16 + lr) * 64 +                     \
            (((kk * 4 + lg) ^ lx) * 8)];                                      \
    _Pragma("unroll") for (int ni = 0; ni < 2; ni++)                          \
      _Pragma("unroll") for (int kk = 0; kk < 2; kk++)                        \
        bq[ni][kk] = *(const bf16x8*)&AB[BUF][1][                             \
            ((QN) * 128 + wc2 * 32 + ni * 16 + lr) * 64 +                     \
            (((kk * 4 + lg) ^ lx) * 8)];                                      \
    STAGE(SBUF, SAB, SHALF, SKO)                                              \
    if (DOVM) { asm volatile("s_waitcnt vmcnt(4)" ::: "memory"); }            \
    __builtin_amdgcn_sched_barrier(0);                                        \
    __builtin_amdgcn_s_barrier();                                             \
    __builtin_amdgcn_sched_barrier(0);                                        \
    __builtin_amdgcn_s_setprio(1);                                            \
    _Pragma("unroll") for (int kk = 0; kk < 2; kk++)                          \
      _Pragma("unroll") for (int mi = 0; mi < 4; mi++)                        \
        _Pragma("unroll") for (int ni = 0; ni < 2; ni++)                      \
          acc[QM][mi][QN][ni] = __builtin_amdgcn_mfma_f32_16x16x32_bf16(      \
              af[mi][kk], bq[ni][kk], acc[QM][mi][QN][ni], 0, 0, 0);          \
    __builtin_amdgcn_s_setprio(0);                                            \
    __builtin_amdgcn_sched_barrier(0);                                        \
    __builtin_amdgcn_s_barrier();                                             \
    __builtin_amdgcn_sched_barrier(0);                                        \
  }

  STAGE(0, 0, 0, 0) STAGE(0, 1, 0, 0) STAGE(0, 0, 1, 0) STAGE(0, 1, 1, 0)
  STAGE(1, 0, 0, 64) STAGE(1, 1, 0, 64)
  asm volatile("s_waitcnt vmcnt(4)" ::: "memory");
  __builtin_amdgcn_sched_barrier(0);
  __builtin_amdgcn_s_barrier();
  __builtin_amdgcn_sched_barrier(0);

  int nit = K >> 7;  // 2 K-tiles (128) per iteration
  for (int it = 0; it < nit; it++) {
    int kb = it << 7;
    PHASE(0, 0, 0,  1, 0, 1, kb + 64,  0)
    PHASE(0, 0, 1,  1, 1, 1, kb + 64,  0)
    PHASE(0, 1, 0,  0, 0, 0, kb + 128, 0)
    PHASE(0, 1, 1,  0, 1, 0, kb + 128, 1)
    PHASE(1, 0, 0,  0, 0, 1, kb + 128, 0)
    PHASE(1, 0, 1,  0, 1, 1, kb + 128, 0)
    PHASE(1, 1, 0,  1, 0, 0, kb + 192, 0)
    PHASE(1, 1, 1,  1, 1, 0, kb + 192, 1)
  }
#undef PHASE
#undef STAGE

  int crow = m0 + wr2 * 64 + lg * 4;
  int ccol = n0 + wc2 * 32 + lr;
  bool doRope = (rc != nullptr) && (n0 >= 2048) && (n0 < 2560);
#pragma unroll
  for (int qm = 0; qm < 2; qm++)
#pragma unroll
    for (int mi = 0; mi < 4; mi++)
#pragma unroll
      for (int qn = 0; qn < 2; qn++)
#pragma unroll
        for (int ni = 0; ni < 2; ni++) {
          int rowb = crow + qm * 128 + mi * 16;
          int col = ccol + qn * 128 + ni * 16;
          if (doRope) {
            int dp = (col >> 1) & 63;
            bool ev = !(col & 1);
#pragma unroll
            for (int r = 0; r < 4; r++) {
              int t = (rowb + r) & (SEQT - 1);
              float c = rc[t * 64 + dp], s = rs[t * 64 + dp];
              float vv = acc[qm][mi][qn][ni][r];
              float pp = __shfl_xor(vv, 1);
              float ov = ev ? (vv * c - pp * s) : (pp * s + vv * c);
              C[(size_t)(rowb + r) * ldc + col] = (OutT)ov;
            }
          } else {
#pragma unroll
            for (int r = 0; r < 4; r++)
              C[(size_t)(rowb + r) * ldc + col] = (OutT)acc[qm][mi][qn][ni][r];
          }
        }
}

// ---------- 8-phase 256x128 GEMM (full-fill variant) ----------
template <typename OutT>
__global__ __launch_bounds__(512, 2) void k_gemm8n(const bf16* __restrict__ A,
                                                   const bf16* __restrict__ Bt,
                                                   OutT* __restrict__ C,
                                                   int nbx, int K, int ldc) {
  __shared__ bf16 Al[2][16384];  // [buf][256 rows x 64 cols]
  __shared__ bf16 Bl[2][8192];   // [buf][128 rows x 64 cols]
  int nb = gridDim.x;
  int cpx = nb >> 3;
  int bid = blockIdx.x;
  int sw = (bid & 7) * cpx + (bid >> 3);
  int bx = sw % nbx, by = sw / nbx;
  int m0 = by << 8, n0 = bx << 7;
  int tid = threadIdx.x;
  int lane = tid & 63, wid = tid >> 6;
  int wr2 = wid >> 2, wc2 = wid & 3;
  int lr = lane & 15, lg = lane >> 4;
  int lx = lr & 7;

  f32x4 acc[2][4][2] = {};

  int srow = tid >> 3;
  int ssl8 = ((tid & 7) ^ (srow & 7)) * 8;

#define STAGEA(SBUF, SHALF, KO)                                               \
  {                                                                           \
    int ko = (KO) <= (K - 64) ? (KO) : 0;                                     \
    int rb = m0 + (SHALF) * 128 + srow;                                       \
    glds16(A + (size_t)rb * K + ko + ssl8,                                    \
           &Al[SBUF][(SHALF) * 8192 + tid * 8]);                              \
    glds16(A + (size_t)(rb + 64) * K + ko + ssl8,                             \
           &Al[SBUF][(SHALF) * 8192 + (512 + tid) * 8]);                      \
  }
#define STAGEB(SBUF, SHALF, KO)                                               \
  {                                                                           \
    int ko = (KO) <= (K - 64) ? (KO) : 0;                                     \
    int rb = n0 + (SHALF) * 64 + srow;                                        \
    glds16(Bt + (size_t)rb * K + ko + ssl8,                                   \
           &Bl[SBUF][(SHALF) * 4096 + tid * 8]);                              \
  }

#define PHASEN(BUF, QM, QN, STG, DOVM)                                        \
  {                                                                           \
    bf16x8 af[4][2], bq[2];                                                   \
    _Pragma("unroll") for (int mi = 0; mi < 4; mi++)                          \
      _Pragma("unroll") for (int kk = 0; kk < 2; kk++)                        \
        af[mi][kk] = *(const bf16x8*)&Al[BUF][                                \
            (QM) * 8192 + (wr2 * 64 + mi * 16 + lr) * 64 +                    \
            (((kk * 4 + lg) ^ lx) * 8)];                                      \
    _Pragma("unroll") for (int kk = 0; kk < 2; kk++)                          \
      bq[kk] = *(const bf16x8*)&Bl[BUF][                                      \
          (QN) * 4096 + (wc2 * 16 + lr) * 64 + (((kk * 4 + lg) ^ lx) * 8)];   \
    STG                                                                       \
    if (DOVM) { asm volatile("s_waitcnt vmcnt(3)" ::: "memory"); }            \
    __builtin_amdgcn_sched_barrier(0);                                        \
    __builtin_amdgcn_s_barrier();                                             \
    __builtin_amdgcn_sched_barrier(0);                                        \
    __builtin_amdgcn_s_setprio(1);                                            \
    _Pragma("unroll") for (int kk = 0; kk < 2; kk++)                          \
      _Pragma("unroll") for (int mi = 0; mi < 4; mi++)                        \
        acc[QM][mi][QN] = __builtin_amdgcn_mfma_f32_16x16x32_bf16(            \
            af[mi][kk], bq[kk], acc[QM][mi][QN], 0, 0, 0);                    \
    __builtin_amdgcn_s_setprio(0);                                            \
    __builtin_amdgcn_sched_barrier(0);                                        \
    __builtin_amdgcn_s_barrier();                                             \
    __builtin_amdgcn_sched_barrier(0);                                        \
  }

  STAGEA(0, 0, 0) STAGEA(0, 1, 0) STAGEB(0, 0, 0) STAGEB(0, 1, 0)
  STAGEA(1, 0, 64) STAGEB(1, 0, 64)
  asm volatile("s_waitcnt vmcnt(3)" ::: "memory");
  __builtin_amdgcn_sched_barrier(0);
  __builtin_amdgcn_s_barrier();
  __builtin_amdgcn_sched_barrier(0);

  int nit = K >> 7;
  for (int it = 0; it < nit; it++) {
    int kb = it << 7;
    PHASEN(0, 0, 0, STAGEA(1, 1, kb + 64),  0)
    PHASEN(0, 0, 1, STAGEB(1, 1, kb + 64),  0)
    PHASEN(0, 1, 0, STAGEA(0, 0, kb + 128), 0)
    PHASEN(0, 1, 1, STAGEB(0, 0, kb + 128), 1)
    PHASEN(1, 0, 0, STAGEA(0, 1, kb + 128), 0)
    PHASEN(1, 0, 1, STAGEB(0, 1, kb + 128), 0)
    PHASEN(1, 1, 0, STAGEA(1, 0, kb + 192), 0)
    PHASEN(1, 1, 1, STAGEB(1, 0, kb + 192), 1)
  }
#undef PHASEN
#undef STAGEB
#undef STAGEA

  int crow = m0 + wr2 * 64 + lg * 4;
  int ccol = n0 + wc2 * 16 + lr;
#pragma unroll
  for (int qm = 0; qm < 2; qm++)
#pragma unroll
    for (int mi = 0; mi < 4; mi++)
#pragma unroll
      for (int qn = 0; qn < 2; qn++)
#pragma unroll
        for (int r = 0; r < 4; r++)
          C[(size_t)(crow + qm * 128 + mi * 16 + r) * ldc +
            ccol + qn * 64] = (OutT)acc[qm][mi][qn][r];
}

// ---------- fused causal flash attention (+Q RoPE), GQA 4:1, 32x32 ----------
// R15-verified structure (R16's chain-split regressed and is reverted).
// K heads arrive pre-roped from the GEMM epilogue.
// NOTE (256,2): (256,3) SPILLS accumulators (R9: FETCH 24.6->220MB).
__global__ __launch_bounds__(256, 2) void k_attn(const bf16* __restrict__ qkv,
                                                 bf16* __restrict__ attout,
                                                 const float* __restrict__ fcos,
                                                 const float* __restrict__ fsin) {
  __shared__ bf16 Kl[2][8192];        // [64][128] per buffer
  __shared__ bf16 Vt[2][128][72];
  __shared__ float Tabs[4][4][32];    // 0: alpha / M, 1: L, 2: F, 3: I
  int bid = blockIdx.x;
  int qt = 31 - (bid >> 5);           // heavy causal tiles dispatch first
  int bh = bid & 31;
  int b = bh >> 4, h = bh & 15, kvh = h >> 2;
  int tid = threadIdx.x, wid = tid >> 6, lane = tid & 63;
  int kvhalf = wid >> 1, wq = wid & 1;
  int li = lane & 31, hi = lane >> 5;
  int q0 = qt * 64;
  int qmin = q0 + wq * 32, qmax = qmin + 31;
  int qlane = qmin + li;
  const float C1 = 0.12751744979927212f;  // (1/sqrt(128)) * log2(e)

  const bf16* kgbase = qkv + (size_t)b * SEQT * 3072 + 2048 + kvh * HD;
  const bf16* vgbase = kgbase + 512;

  // Q B-frags with fused RoPE (one-time): dp = ks*8 + hi*4 + j
  bf16x8 qf[8];
  {
    const bf16* qb = qkv + (size_t)(b * SEQT + qlane) * 3072 + h * HD + hi * 8;
    const float* cb = fcos + qlane * 64 + hi * 4;
    const float* sb = fsin + qlane * 64 + hi * 4;
#pragma unroll
    for (int ks = 0; ks < 8; ks++) {
      bf16x8 v = *(const bf16x8*)(qb + ks * 16);
      f32x4 c = *(const f32x4*)(cb + ks * 8);
      f32x4 s = *(const f32x4*)(sb + ks * 8);
#pragma unroll
      for (int j = 0; j < 4; j++) {
        float a = (float)v[2 * j], bb = (float)v[2 * j + 1];
        qf[ks][2 * j]     = (bf16)(a * c[j] - bb * s[j]);
        qf[ks][2 * j + 1] = (bf16)(a * s[j] + bb * c[j]);
      }
    }
  }

  float mrun = -INFINITY, lpart = 0.f;
  f32x16 o0 = {}, o1 = {}, o2 = {}, o3 = {};
  int nkt = qt + 1;
  int kvbase = 32 * kvhalf;

  int g = (lane >> 4) & 3;
  int lr = lane & 15;
  int kq4 = (wid * 4 + g) * 4;
  int dc = lr * 8;
  int xr = (lr & 7) << 3;
  int kvw = kq4 ^ xr;

  bf16x8 vr0, vr1, vr2, vr3;

#pragma unroll
  for (int r = 0; r < 4; r++) {
    int ci = r * 256 + tid;
    int row = ci >> 4;
    int sl = (ci & 15) ^ (row & 15);
    glds16(kgbase + (size_t)row * 3072 + sl * 8, &Kl[0][ci * 8]);
  }
  {
    const bf16* vrow = vgbase + (size_t)kq4 * 3072 + dc;
    vr0 = *(const bf16x8*)(vrow);
    vr1 = *(const bf16x8*)(vrow + 3072);
    vr2 = *(const bf16x8*)(vrow + 6144);
    vr3 = *(const bf16x8*)(vrow + 9216);
  }

  for (int kt = 0; kt < nkt; kt++) {
    int cur = kt & 1;
    int kv0 = kt * 64;
    asm volatile("s_waitcnt vmcnt(0)" ::: "memory");

#pragma unroll
    for (int j = 0; j < 8; j++) {
      bf16x4 w;
      w[0] = vr0[j]; w[1] = vr1[j]; w[2] = vr2[j]; w[3] = vr3[j];
      *(bf16x4*)&Vt[cur][dc + j][kvw] = w;
    }

    asm volatile("s_waitcnt lgkmcnt(0)" ::: "memory");
    __builtin_amdgcn_sched_barrier(0);
    __builtin_amdgcn_s_barrier();
    __builtin_amdgcn_sched_barrier(0);

    if (kt + 1 < nkt) {
      int kv1 = kv0 + 64;
      bf16* kdst = &Kl[cur ^ 1][0];
#pragma unroll
      for (int r = 0; r < 4; r++) {
        int ci = r * 256 + tid;
        int row = ci >> 4;
        int sl = (ci & 15) ^ (row & 15);
        glds16(kgbase + (size_t)(kv1 + row) * 3072 + sl * 8, kdst + ci * 8);
      }
      const bf16* vrow = vgbase + (size_t)(kv1 + kq4) * 3072 + dc;
      vr0 = *(const bf16x8*)(vrow);
      vr1 = *(const bf16x8*)(vrow + 3072);
      vr2 = *(const bf16x8*)(vrow + 6144);
      vr3 = *(const bf16x8*)(vrow + 9216);
    }

    if (kv0 + kvbase <= qmax) {
      f32x16 s0 = {};
      const char* kb0 = (const char*)&Kl[cur][0] + kvhalf * 8192 + li * 256;
      __builtin_amdgcn_s_setprio(1);
#pragma unroll
      for (int ks = 0; ks < 8; ks++) {
        int off = ((ks * 2 + hi) ^ (li & 15)) << 4;
        bf16x8 kf0 = *(const bf16x8*)(kb0 + off);
        s0 = __builtin_amdgcn_mfma_f32_32x32x16_bf16(kf0, qf[ks], s0, 0, 0, 0);
      }
      __builtin_amdgcn_s_setprio(0);

      if (kv0 + kvbase + 31 > qmin) {
        int base0 = kv0 + kvbase + 4 * hi - qlane;
#pragma unroll
        for (int r = 0; r < 16; r++) {
          int off = (r & 3) + 8 * (r >> 2);
          if (base0 + off > 0) s0[r] = -INFINITY;
        }
      }

      float pm = s0[0];
#pragma unroll
      for (int r = 1; r < 16; r++) pm = fmaxf(pm, s0[r]);
      pm = fmaxf(pm, __shfl_xor(pm, 32));

      if (!__all(pm - mrun <= 62.0f)) {
        float mnew = fmaxf(mrun, pm);
        float alpha = exp2f((mrun - mnew) * C1);
        mrun = mnew;
        lpart *= alpha;
        Tabs[0][wid][li] = alpha;
        asm volatile("s_waitcnt lgkmcnt(0)" ::: "memory");
        f32x4 a0 = *(const f32x4*)&Tabs[0][wid][4 * hi];
        f32x4 a1 = *(const f32x4*)&Tabs[0][wid][4 * hi + 8];
        f32x4 a2 = *(const f32x4*)&Tabs[0][wid][4 * hi + 16];
        f32x4 a3 = *(const f32x4*)&Tabs[0][wid][4 * hi + 24];
#define RESC_RR(rr, av)                                            \
  _Pragma("unroll") for (int i = 0; i < 4; i++) {                  \
    float f = av[i];                                               \
    o0[rr * 4 + i] *= f; o1[rr * 4 + i] *= f;                      \
    o2[rr * 4 + i] *= f; o3[rr * 4 + i] *= f;                      \
  }
        RESC_RR(0, a0) RESC_RR(1, a1) RESC_RR(2, a2) RESC_RR(3, a3)
#undef RESC_RR
      }

      float mC = mrun * C1;
      float rs = 0.f;
#pragma unroll
      for (int r = 0; r < 16; r++) {
        float p = exp2f(fmaf(s0[r], C1, -mC));
        s0[r] = p; rs += p;
      }
      lpart += rs;

      union U4 { unsigned int u[4]; bf16x8 v; };
      U4 pa0, pa1;
      {
        unsigned int e0 = cvtpk(s0[0], s0[1]), e1 = cvtpk(s0[2], s0[3]);
        unsigned int e2 = cvtpk(s0[4], s0[5]), e3 = cvtpk(s0[6], s0[7]);
        unsigned int e4 = cvtpk(s0[8], s0[9]), e5 = cvtpk(s0[10], s0[11]);
        unsigned int e6 = cvtpk(s0[12], s0[13]), e7 = cvtpk(s0[14], s0[15]);
        unsigned int t0 = __shfl_xor(e0, 32), t1 = __shfl_xor(e1, 32);
        unsigned int t2 = __shfl_xor(e2, 32), t3 = __shfl_xor(e3, 32);
        unsigned int t4 = __shfl_xor(e4, 32), t5 = __shfl_xor(e5, 32);
        unsigned int t6 = __shfl_xor(e6, 32), t7 = __shfl_xor(e7, 32);
        pa0.u[0] = hi ? t2 : e0;  pa0.u[1] = hi ? t3 : e1;
        pa0.u[2] = hi ? e2 : t0;  pa0.u[3] = hi ? e3 : t1;
        pa1.u[0] = hi ? t6 : e4;  pa1.u[1] = hi ? t7 : e5;
        pa1.u[2] = hi ? e6 : t4;  pa1.u[3] = hi ? e7 : t5;
      }

      __builtin_amdgcn_s_setprio(1);
#define PV_DB(OACC, DB)                                                      \
  {                                                                          \
    int d = DB * 32 + li;                                                    \
    int xv = ((d >> 3) & 7) << 3;                                            \
    bf16x8 vb0 = *(const bf16x8*)&Vt[cur][d][(kvbase + hi * 8) ^ xv];        \
    bf16x8 vb1 = *(const bf16x8*)&Vt[cur][d][(kvbase + 16 + hi * 8) ^ xv];   \
    OACC = __builtin_amdgcn_mfma_f32_32x32x16_bf16(pa0.v, vb0, OACC, 0, 0, 0); \
    OACC = __builtin_amdgcn_mfma_f32_32x32x16_bf16(pa1.v, vb1, OACC, 0, 0, 0); \
  }
      PV_DB(o0, 0) PV_DB(o1, 1) PV_DB(o2, 2) PV_DB(o3, 3)
#undef PV_DB
      __builtin_amdgcn_s_setprio(0);
    }
  }

  // ---- epilogue: flash-merge kv-half pairs (w, w^2), then store ----
  lpart += __shfl_xor(lpart, 32);
  Tabs[0][wid][li] = mrun;   // M
  Tabs[1][wid][li] = lpart;  // L
  asm volatile("s_waitcnt lgkmcnt(0)" ::: "memory");
  __builtin_amdgcn_s_barrier();
  int peer = wid ^ 2;
  float mP = Tabs[0][peer][li], lP = Tabs[1][peer][li];
  float mS = fmaxf(mrun, mP);
  float fMe = exp2f((mrun - mS) * C1);
  float fPe = exp2f((mP - mS) * C1);
  float lTot = lpart * fMe + lP * fPe;
  Tabs[2][wid][li] = fMe;          // F (own factor)
  Tabs[3][wid][li] = 1.f / lTot;   // I (same for both waves of the pair)
  asm volatile("s_waitcnt lgkmcnt(0)" ::: "memory");
  __builtin_amdgcn_s_barrier();
  f32x4 Fv0 = *(const f32x4*)&Tabs[2][wid][4 * hi];
  f32x4 Fv1 = *(const f32x4*)&Tabs[2][wid][4 * hi + 8];
  f32x4 Fv2 = *(const f32x4*)&Tabs[2][wid][4 * hi + 16];
  f32x4 Fv3 = *(const f32x4*)&Tabs[2][wid][4 * hi + 24];
  f32x4 Iv0 = *(const f32x4*)&Tabs[3][wid][4 * hi];
  f32x4 Iv1 = *(const f32x4*)&Tabs[3][wid][4 * hi + 8];
  f32x4 Iv2 = *(const f32x4*)&Tabs[3][wid][4 * hi + 16];
  f32x4 Iv3 = *(const f32x4*)&Tabs[3][wid][4 * hi + 24];

  float* X = (float*)&Kl[0][0];  // 2 exchange buffers of 4096 floats (32 KB)
  float* Xb = X + (wid & 1) * 4096;
  if (kvhalf == 1) {
#define XW_RR(OACC, DB, rr, Fv)                                              \
  _Pragma("unroll") for (int i = 0; i < 4; i++)                              \
    Xb[(4 * hi + 8 * rr + i) * 128 + DB * 32 + li] = OACC[rr * 4 + i] * Fv[i];
#define XW_DB(OACC, DB) XW_RR(OACC, DB, 0, Fv0) XW_RR(OACC, DB, 1, Fv1) \
                        XW_RR(OACC, DB, 2, Fv2) XW_RR(OACC, DB, 3, Fv3)
    XW_DB(o0, 0) XW_DB(o1, 1) XW_DB(o2, 2) XW_DB(o3, 3)
#undef XW_DB
#undef XW_RR
  }
  asm volatile("s_waitcnt lgkmcnt(0)" ::: "memory");
  __builtin_amdgcn_s_barrier();
  if (kvhalf == 0) {
#define XR_RR(OACC, DB, rr, Fv)                                              \
  _Pragma("unroll") for (int i = 0; i < 4; i++)                              \
    OACC[rr * 4 + i] = OACC[rr * 4 + i] * Fv[i] +                            \
        Xb[(4 * hi + 8 * rr + i) * 128 + DB * 32 + li];
#define XR_DB(OACC, DB) XR_RR(OACC, DB, 0, Fv0) XR_RR(OACC, DB, 1, Fv1) \
                        XR_RR(OACC, DB, 2, Fv2) XR_RR(OACC, DB, 3, Fv3)
    XR_DB(o0, 0) XR_DB(o1, 1) XR_DB(o2, 2) XR_DB(o3, 3)
#undef XR_DB
#undef XR_RR
    size_t obase = (size_t)(b * SEQT) * 2048 + h * HD;
#define STORE_RR(rr, lv)                                                     \
  _Pragma("unroll") for (int i = 0; i < 4; i++) {                            \
    int q = qmin + 4 * hi + 8 * rr + i;                                      \
    size_t rowb = obase + (size_t)q * 2048 + li;                             \
    attout[rowb + 0]  = (bf16)(o0[rr * 4 + i] * lv[i]);                      \
    attout[rowb + 32] = (bf16)(o1[rr * 4 + i] * lv[i]);                      \
    attout[rowb + 64] = (bf16)(o2[rr * 4 + i] * lv[i]);                      \
    attout[rowb + 96] = (bf16)(o3[rr * 4 + i] * lv[i]);                      \
  }
    STORE_RR(0, Iv0) STORE_RR(1, Iv1) STORE_RR(2, Iv2) STORE_RR(3, Iv3)
#undef STORE_RR
  }
}

extern "C" void kernel_launch(void* const* d_in, const int* in_sizes, int n_in,
                              void* d_out, int out_size, void* d_ws, size_t ws_size,
                              hipStream_t stream) {
  const float* x    = (const float*)d_in[0];
  const float* fcos = (const float*)d_in[1];
  const float* fsin = (const float*)d_in[2];
  const float* wq   = (const float*)d_in[3];
  const float* wk   = (const float*)d_in[4];
  const float* wv   = (const float*)d_in[5];
  const float* wo   = (const float*)d_in[6];
  float* out = (float*)d_out;

  // ws layout (bytes): [XB/ATT 16.78M][W 12.58M][QKV 25.17M][WOT 8.39M opt]
  char* ws = (char*)d_ws;
  bf16* XB  = (bf16*)ws;                                    // 4096x2048, later attn out
  bf16* W   = (bf16*)(ws + 16777216);                       // 3072x2048 (B^T panel)
  bf16* QKV = (bf16*)(ws + 16777216 + 12582912);            // 4096x3072
  bool bigws = ws_size >= 62914560ull;
  bf16* WOT = bigws ? (bf16*)(ws + 54525952) : W;           // 2048x2048 wo^T

  dim3 tb(32, 8);
  if (bigws) {
    k_transpose4<<<dim3(160, 64), tb, 0, stream>>>(wq, wk, wv, wo, W, WOT);
  } else {
    k_transpose3<<<dim3(96, 64), tb, 0, stream>>>(wq, wk, wv, W);
  }
  k_convert<<<4096, 256, 0, stream>>>(x, XB, 1048576);
  k_gemm8<bf16><<<192, 512, 0, stream>>>(XB, W, QKV, 12, 2048, 3072, fcos, fsin);
  k_attn<<<1024, 256, 0, stream>>>(QKV, XB, fcos, fsin);
  if (!bigws) {
    k_transpose<<<dim3(64, 64), tb, 0, stream>>>(wo, W, 2048, 2048);
  }
  k_gemm8n<float><<<256, 512, 0, stream>>>(XB, WOT, out, 16, 2048, 2048);
}

// Round 18
// 218.830 us; speedup vs baseline: 1.0149x; 1.0149x over previous
//
#include <hip/hip_runtime.h>
#include <hip/hip_bf16.h>

#define SEQT 2048
#define NH 16
#define HD 128

typedef __bf16 bf16;
typedef __bf16 bf16x4 __attribute__((ext_vector_type(4)));
typedef __bf16 bf16x8 __attribute__((ext_vector_type(8)));
typedef float f32x4 __attribute__((ext_vector_type(4)));
typedef float f32x16 __attribute__((ext_vector_type(16)));

__device__ inline void glds16(const bf16* g, bf16* l) {
  __builtin_amdgcn_global_load_lds(
      (const __attribute__((address_space(1))) unsigned int*)g,
      (__attribute__((address_space(3))) unsigned int*)l, 16, 0, 0);
}

__device__ inline unsigned int cvtpk(float a, float b) {
  unsigned int d;
  asm("v_cvt_pk_bf16_f32 %0, %1, %2" : "=v"(d) : "v"(a), "v"(b));
  return d;
}

// ---------- fp32 -> bf16 elementwise convert (8 elems/thread) ----------
__global__ __launch_bounds__(256) void k_convert(const float* __restrict__ in,
                                                 bf16* __restrict__ out, int n8) {
  int i = blockIdx.x * 256 + threadIdx.x;
  if (i >= n8) return;
  const float4* p = (const float4*)in + (size_t)i * 2;
  float4 a = p[0], b = p[1];
  bf16x8 o;
  o[0] = (bf16)a.x; o[1] = (bf16)a.y; o[2] = (bf16)a.z; o[3] = (bf16)a.w;
  o[4] = (bf16)b.x; o[5] = (bf16)b.y; o[6] = (bf16)b.z; o[7] = (bf16)b.w;
  *((bf16x8*)out + i) = o;
}

// ---------- transpose + convert: in (R x C) fp32 -> out (C x R) bf16 ----------
__global__ __launch_bounds__(256) void k_transpose(const float* __restrict__ in,
                                                   bf16* __restrict__ out, int R, int C) {
  __shared__ float tile[32][33];
  int c0 = blockIdx.x * 32, r0 = blockIdx.y * 32;
  int tx = threadIdx.x, ty = threadIdx.y;  // blockDim (32,8)
#pragma unroll
  for (int i = 0; i < 4; i++)
    tile[ty + i * 8][tx] = in[(size_t)(r0 + ty + i * 8) * C + c0 + tx];
  __syncthreads();
#pragma unroll
  for (int i = 0; i < 4; i++) {
    int r = ty + i * 8;
    out[(size_t)(c0 + r) * R + r0 + tx] = (bf16)tile[tx][r];
  }
}

// ---------- fused transpose of wq/wk/wv (and optionally wo) ----------
__global__ __launch_bounds__(256) void k_transpose3(const float* __restrict__ wq,
                                                    const float* __restrict__ wk,
                                                    const float* __restrict__ wv,
                                                    bf16* __restrict__ W) {
  __shared__ float tile[32][33];
  int bx = blockIdx.x;
  const float* src;
  bf16* dst;
  int C;
  if (bx < 64) {
    src = wq; dst = W; C = 2048;
  } else if (bx < 80) {
    src = wk; dst = W + 2048 * 2048; C = 512; bx -= 64;
  } else {
    src = wv; dst = W + 2560 * 2048; C = 512; bx -= 80;
  }
  int c0 = bx * 32, r0 = blockIdx.y * 32;
  int tx = threadIdx.x, ty = threadIdx.y;  // blockDim (32,8)
#pragma unroll
  for (int i = 0; i < 4; i++)
    tile[ty + i * 8][tx] = src[(size_t)(r0 + ty + i * 8) * C + c0 + tx];
  __syncthreads();
#pragma unroll
  for (int i = 0; i < 4; i++) {
    int r = ty + i * 8;
    dst[(size_t)(c0 + r) * 2048 + r0 + tx] = (bf16)tile[tx][r];
  }
}

__global__ __launch_bounds__(256) void k_transpose4(const float* __restrict__ wq,
                                                    const float* __restrict__ wk,
                                                    const float* __restrict__ wv,
                                                    const float* __restrict__ wo,
                                                    bf16* __restrict__ W,
                                                    bf16* __restrict__ WOT) {
  __shared__ float tile[32][33];
  int bx = blockIdx.x;
  const float* src;
  bf16* dst;
  int C;
  if (bx < 64) {
    src = wq; dst = W; C = 2048;
  } else if (bx < 80) {
    src = wk; dst = W + 2048 * 2048; C = 512; bx -= 64;
  } else if (bx < 96) {
    src = wv; dst = W + 2560 * 2048; C = 512; bx -= 80;
  } else {
    src = wo; dst = WOT; C = 2048; bx -= 96;
  }
  int c0 = bx * 32, r0 = blockIdx.y * 32;
  int tx = threadIdx.x, ty = threadIdx.y;  // blockDim (32,8)
#pragma unroll
  for (int i = 0; i < 4; i++)
    tile[ty + i * 8][tx] = src[(size_t)(r0 + ty + i * 8) * C + c0 + tx];
  __syncthreads();
#pragma unroll
  for (int i = 0; i < 4; i++) {
    int r = ty + i * 8;
    dst[(size_t)(c0 + r) * 2048 + r0 + tx] = (bf16)tile[tx][r];
  }
}

// ---------- 8-phase 256x256 bf16 GEMM (T3+T4 schedule, m201-style) ----------
template <typename OutT>
__global__ __launch_bounds__(512, 2) void k_gemm8(const bf16* __restrict__ A,
                                                  const bf16* __restrict__ Bt,
                                                  OutT* __restrict__ C,
                                                  int nbx, int K, int ldc) {
  __shared__ bf16 AB[2][2][16384];  // [buf][0=A,1=B][256 rows x 64 cols]
  int nb = gridDim.x;               // multiple of 8
  int cpx = nb >> 3;
  int bid = blockIdx.x;
  int sw = (bid & 7) * cpx + (bid >> 3);  // XCD-aware swizzle (bijective)
  int bx = sw % nbx, by = sw / nbx;
  int m0 = by << 8, n0 = bx << 8;
  int tid = threadIdx.x;
  int lane = tid & 63, wid = tid >> 6;
  int wr2 = wid >> 2, wc2 = wid & 3;
  int lr = lane & 15, lg = lane >> 4;
  int lx = lr & 7;

  f32x4 acc[2][4][2][2] = {};

  int srow = tid >> 3;
  int ssl8 = ((tid & 7) ^ (srow & 7)) * 8;  // pre-swizzled source col offset

#define STAGE(SBUF, SAB, SHALF, KO)                                           \
  {                                                                           \
    int ko = (KO) <= (K - 64) ? (KO) : 0;                                     \
    const bf16* gb = (SAB) ? Bt : A;                                          \
    int rb = ((SAB) ? n0 : m0) + (SHALF) * 128 + srow;                        \
    glds16(gb + (size_t)rb * K + ko + ssl8,                                   \
           &AB[SBUF][SAB][(SHALF) * 8192 + tid * 8]);                         \
    glds16(gb + (size_t)(rb + 64) * K + ko + ssl8,                            \
           &AB[SBUF][SAB][(SHALF) * 8192 + (512 + tid) * 8]);                 \
  }

#define PHASE(BUF, QM, QN, SBUF, SAB, SHALF, SKO, DOVM)                       \
  {                                                                           \
    bf16x8 af[4][2], bq[2][2];                                                \
    _Pragma("unroll") for (int mi = 0; mi < 4; mi++)                          \
      _Pragma("unroll") for (int kk = 0; kk < 2; kk++)                        \
        af[mi][kk] = *(const bf16x8*)&AB[BUF][0][                             \
            ((QM) * 128 + wr2 * 64 + mi * 16 + lr) * 64 +                     \
            (((kk * 4 + lg) ^ lx) * 8)];                                      \
    _Pragma("unroll") for (int ni = 0; ni < 2; ni++)                          \
      _Pragma("unroll") for (int kk = 0; kk < 2; kk++)                        \
        bq[ni][kk] = *(const bf16x8*)&AB[BUF][1][                             \
            ((QN) * 128 + wc2 * 32 + ni * 16 + lr) * 64 +                     \
            (((kk * 4 + lg) ^ lx) * 8)];                                      \
    STAGE(SBUF, SAB, SHALF, SKO)                                              \
    if (DOVM) { asm volatile("s_waitcnt vmcnt(4)" ::: "memory"); }            \
    __builtin_amdgcn_sched_barrier(0);                                        \
    __builtin_amdgcn_s_barrier();                                             \
    __builtin_amdgcn_sched_barrier(0);                                        \
    __builtin_amdgcn_s_setprio(1);                                            \
    _Pragma("unroll") for (int kk = 0; kk < 2; kk++)                          \
      _Pragma("unroll") for (int mi = 0; mi < 4; mi++)                        \
        _Pragma("unroll") for (int ni = 0; ni < 2; ni++)                      \
          acc[QM][mi][QN][ni] = __builtin_amdgcn_mfma_f32_16x16x32_bf16(      \
              af[mi][kk], bq[ni][kk], acc[QM][mi][QN][ni], 0, 0, 0);          \
    __builtin_amdgcn_s_setprio(0);                                            \
    __builtin_amdgcn_sched_barrier(0);                                        \
    __builtin_amdgcn_s_barrier();                                             \
    __builtin_amdgcn_sched_barrier(0);                                        \
  }

  STAGE(0, 0, 0, 0) STAGE(0, 1, 0, 0) STAGE(0, 0, 1, 0) STAGE(0, 1, 1, 0)
  STAGE(1, 0, 0, 64) STAGE(1, 1, 0, 64)
  asm volatile("s_waitcnt vmcnt(4)" ::: "memory");
  __builtin_amdgcn_sched_barrier(0);
  __builtin_amdgcn_s_barrier();
  __builtin_amdgcn_sched_barrier(0);

  int nit = K >> 7;  // 2 K-tiles (128) per iteration
  for (int it = 0; it < nit; it++) {
    int kb = it << 7;
    PHASE(0, 0, 0,  1, 0, 1, kb + 64,  0)
    PHASE(0, 0, 1,  1, 1, 1, kb + 64,  0)
    PHASE(0, 1, 0,  0, 0, 0, kb + 128, 0)
    PHASE(0, 1, 1,  0, 1, 0, kb + 128, 1)
    PHASE(1, 0, 0,  0, 0, 1, kb + 128, 0)
    PHASE(1, 0, 1,  0, 1, 1, kb + 128, 0)
    PHASE(1, 1, 0,  1, 0, 0, kb + 192, 0)
    PHASE(1, 1, 1,  1, 1, 0, kb + 192, 1)
  }
#undef PHASE
#undef STAGE

  int crow = m0 + wr2 * 64 + lg * 4;
  int ccol = n0 + wc2 * 32 + lr;
#pragma unroll
  for (int qm = 0; qm < 2; qm++)
#pragma unroll
    for (int mi = 0; mi < 4; mi++)
#pragma unroll
      for (int qn = 0; qn < 2; qn++)
#pragma unroll
        for (int ni = 0; ni < 2; ni++)
#pragma unroll
          for (int r = 0; r < 4; r++)
            C[(size_t)(crow + qm * 128 + mi * 16 + r) * ldc +
              ccol + qn * 128 + ni * 16] = (OutT)acc[qm][mi][qn][ni][r];
}

// ---------- 8-phase 256x128 GEMM (full-fill variant) ----------
template <typename OutT>
__global__ __launch_bounds__(512, 2) void k_gemm8n(const bf16* __restrict__ A,
                                                   const bf16* __restrict__ Bt,
                                                   OutT* __restrict__ C,
                                                   int nbx, int K, int ldc) {
  __shared__ bf16 Al[2][16384];  // [buf][256 rows x 64 cols]
  __shared__ bf16 Bl[2][8192];   // [buf][128 rows x 64 cols]
  int nb = gridDim.x;
  int cpx = nb >> 3;
  int bid = blockIdx.x;
  int sw = (bid & 7) * cpx + (bid >> 3);
  int bx = sw % nbx, by = sw / nbx;
  int m0 = by << 8, n0 = bx << 7;
  int tid = threadIdx.x;
  int lane = tid & 63, wid = tid >> 6;
  int wr2 = wid >> 2, wc2 = wid & 3;
  int lr = lane & 15, lg = lane >> 4;
  int lx = lr & 7;

  f32x4 acc[2][4][2] = {};

  int srow = tid >> 3;
  int ssl8 = ((tid & 7) ^ (srow & 7)) * 8;

#define STAGEA(SBUF, SHALF, KO)                                               \
  {                                                                           \
    int ko = (KO) <= (K - 64) ? (KO) : 0;                                     \
    int rb = m0 + (SHALF) * 128 + srow;                                       \
    glds16(A + (size_t)rb * K + ko + ssl8,                                    \
           &Al[SBUF][(SHALF) * 8192 + tid * 8]);                              \
    glds16(A + (size_t)(rb + 64) * K + ko + ssl8,                             \
           &Al[SBUF][(SHALF) * 8192 + (512 + tid) * 8]);                      \
  }
#define STAGEB(SBUF, SHALF, KO)                                               \
  {                                                                           \
    int ko = (KO) <= (K - 64) ? (KO) : 0;                                     \
    int rb = n0 + (SHALF) * 64 + srow;                                        \
    glds16(Bt + (size_t)rb * K + ko + ssl8,                                   \
           &Bl[SBUF][(SHALF) * 4096 + tid * 8]);                              \
  }

#define PHASEN(BUF, QM, QN, STG, DOVM)                                        \
  {                                                                           \
    bf16x8 af[4][2], bq[2];                                                   \
    _Pragma("unroll") for (int mi = 0; mi < 4; mi++)                          \
      _Pragma("unroll") for (int kk = 0; kk < 2; kk++)                        \
        af[mi][kk] = *(const bf16x8*)&Al[BUF][                                \
            (QM) * 8192 + (wr2 * 64 + mi * 16 + lr) * 64 +                    \
            (((kk * 4 + lg) ^ lx) * 8)];                                      \
    _Pragma("unroll") for (int kk = 0; kk < 2; kk++)                          \
      bq[kk] = *(const bf16x8*)&Bl[BUF][                                      \
          (QN) * 4096 + (wc2 * 16 + lr) * 64 + (((kk * 4 + lg) ^ lx) * 8)];   \
    STG                                                                       \
    if (DOVM) { asm volatile("s_waitcnt vmcnt(3)" ::: "memory"); }            \
    __builtin_amdgcn_sched_barrier(0);                                        \
    __builtin_amdgcn_s_barrier();                                             \
    __builtin_amdgcn_sched_barrier(0);                                        \
    __builtin_amdgcn_s_setprio(1);                                            \
    _Pragma("unroll") for (int kk = 0; kk < 2; kk++)                          \
      _Pragma("unroll") for (int mi = 0; mi < 4; mi++)                        \
        acc[QM][mi][QN] = __builtin_amdgcn_mfma_f32_16x16x32_bf16(            \
            af[mi][kk], bq[kk], acc[QM][mi][QN], 0, 0, 0);                    \
    __builtin_amdgcn_s_setprio(0);                                            \
    __builtin_amdgcn_sched_barrier(0);                                        \
    __builtin_amdgcn_s_barrier();                                             \
    __builtin_amdgcn_sched_barrier(0);                                        \
  }

  STAGEA(0, 0, 0) STAGEA(0, 1, 0) STAGEB(0, 0, 0) STAGEB(0, 1, 0)
  STAGEA(1, 0, 64) STAGEB(1, 0, 64)
  asm volatile("s_waitcnt vmcnt(3)" ::: "memory");
  __builtin_amdgcn_sched_barrier(0);
  __builtin_amdgcn_s_barrier();
  __builtin_amdgcn_sched_barrier(0);

  int nit = K >> 7;
  for (int it = 0; it < nit; it++) {
    int kb = it << 7;
    PHASEN(0, 0, 0, STAGEA(1, 1, kb + 64),  0)
    PHASEN(0, 0, 1, STAGEB(1, 1, kb + 64),  0)
    PHASEN(0, 1, 0, STAGEA(0, 0, kb + 128), 0)
    PHASEN(0, 1, 1, STAGEB(0, 0, kb + 128), 1)
    PHASEN(1, 0, 0, STAGEA(0, 1, kb + 128), 0)
    PHASEN(1, 0, 1, STAGEB(0, 1, kb + 128), 0)
    PHASEN(1, 1, 0, STAGEA(1, 0, kb + 192), 0)
    PHASEN(1, 1, 1, STAGEB(1, 0, kb + 192), 1)
  }
#undef PHASEN
#undef STAGEB
#undef STAGEA

  int crow = m0 + wr2 * 64 + lg * 4;
  int ccol = n0 + wc2 * 16 + lr;
#pragma unroll
  for (int qm = 0; qm < 2; qm++)
#pragma unroll
    for (int mi = 0; mi < 4; mi++)
#pragma unroll
      for (int qn = 0; qn < 2; qn++)
#pragma unroll
        for (int r = 0; r < 4; r++)
          C[(size_t)(crow + qm * 128 + mi * 16 + r) * ldc +
            ccol + qn * 64] = (OutT)acc[qm][mi][qn][r];
}

// ---------- RoPE in-place, K heads only (Q-rope fused into k_attn) ----------
__global__ __launch_bounds__(256) void k_ropek(bf16* __restrict__ qkv,
                                               const float* __restrict__ fcos,
                                               const float* __restrict__ fsin) {
  int gid = blockIdx.x * 256 + threadIdx.x;  // row*32 + head*8 + g8
  int row = gid >> 5;
  int p = gid & 31;
  int head = p >> 3;
  int g8 = p & 7;
  int t = row & (SEQT - 1);
  bf16* ptr = qkv + (size_t)row * 3072 + 2048 + head * HD + g8 * 16;
  bf16x8 v0 = *(const bf16x8*)ptr;
  bf16x8 v1 = *(const bf16x8*)(ptr + 8);
  const f32x4* cp = (const f32x4*)(fcos + t * 64 + g8 * 8);
  const f32x4* sp = (const f32x4*)(fsin + t * 64 + g8 * 8);
  f32x4 c0 = cp[0], c1 = cp[1], s0 = sp[0], s1 = sp[1];
  bf16x8 o0, o1;
#pragma unroll
  for (int k = 0; k < 4; k++) {
    float a0 = (float)v0[2 * k], b0 = (float)v0[2 * k + 1];
    o0[2 * k]     = (bf16)(a0 * c0[k] - b0 * s0[k]);
    o0[2 * k + 1] = (bf16)(a0 * s0[k] + b0 * c0[k]);
    float a1 = (float)v1[2 * k], b1 = (float)v1[2 * k + 1];
    o1[2 * k]     = (bf16)(a1 * c1[k] - b1 * s1[k]);
    o1[2 * k + 1] = (bf16)(a1 * s1[k] + b1 * c1[k]);
  }
  *(bf16x8*)ptr = o0;
  *(bf16x8*)(ptr + 8) = o1;
}

// ---------- fused causal flash attention (+Q RoPE), GQA 4:1, 32x32 ----------
// R15-verified structure. K heads pre-roped by k_ropek.
// NOTE (256,2): (256,3) SPILLS accumulators (R9: FETCH 24.6->220MB).
__global__ __launch_bounds__(256, 2) void k_attn(const bf16* __restrict__ qkv,
                                                 bf16* __restrict__ attout,
                                                 const float* __restrict__ fcos,
                                                 const float* __restrict__ fsin) {
  __shared__ bf16 Kl[2][8192];        // [64][128] per buffer
  __shared__ bf16 Vt[2][128][72];
  __shared__ float Tabs[4][4][32];    // 0: alpha / M, 1: L, 2: F, 3: I
  int bid = blockIdx.x;
  int qt = 31 - (bid >> 5);           // heavy causal tiles dispatch first
  int bh = bid & 31;
  int b = bh >> 4, h = bh & 15, kvh = h >> 2;
  int tid = threadIdx.x, wid = tid >> 6, lane = tid & 63;
  int kvhalf = wid >> 1, wq = wid & 1;
  int li = lane & 31, hi = lane >> 5;
  int q0 = qt * 64;
  int qmin = q0 + wq * 32, qmax = qmin + 31;
  int qlane = qmin + li;
  const float C1 = 0.12751744979927212f;  // (1/sqrt(128)) * log2(e)

  const bf16* kgbase = qkv + (size_t)b * SEQT * 3072 + 2048 + kvh * HD;
  const bf16* vgbase = kgbase + 512;

  // Q B-frags with fused RoPE (one-time): dp = ks*8 + hi*4 + j
  bf16x8 qf[8];
  {
    const bf16* qb = qkv + (size_t)(b * SEQT + qlane) * 3072 + h * HD + hi * 8;
    const float* cb = fcos + qlane * 64 + hi * 4;
    const float* sb = fsin + qlane * 64 + hi * 4;
#pragma unroll
    for (int ks = 0; ks < 8; ks++) {
      bf16x8 v = *(const bf16x8*)(qb + ks * 16);
      f32x4 c = *(const f32x4*)(cb + ks * 8);
      f32x4 s = *(const f32x4*)(sb + ks * 8);
#pragma unroll
      for (int j = 0; j < 4; j++) {
        float a = (float)v[2 * j], bb = (float)v[2 * j + 1];
        qf[ks][2 * j]     = (bf16)(a * c[j] - bb * s[j]);
        qf[ks][2 * j + 1] = (bf16)(a * s[j] + bb * c[j]);
      }
    }
  }

  float mrun = -INFINITY, lpart = 0.f;
  f32x16 o0 = {}, o1 = {}, o2 = {}, o3 = {};
  int nkt = qt + 1;
  int kvbase = 32 * kvhalf;

  int g = (lane >> 4) & 3;
  int lr = lane & 15;
  int kq4 = (wid * 4 + g) * 4;
  int dc = lr * 8;
  int xr = (lr & 7) << 3;
  int kvw = kq4 ^ xr;

  bf16x8 vr0, vr1, vr2, vr3;

#pragma unroll
  for (int r = 0; r < 4; r++) {
    int ci = r * 256 + tid;
    int row = ci >> 4;
    int sl = (ci & 15) ^ (row & 15);
    glds16(kgbase + (size_t)row * 3072 + sl * 8, &Kl[0][ci * 8]);
  }
  {
    const bf16* vrow = vgbase + (size_t)kq4 * 3072 + dc;
    vr0 = *(const bf16x8*)(vrow);
    vr1 = *(const bf16x8*)(vrow + 3072);
    vr2 = *(const bf16x8*)(vrow + 6144);
    vr3 = *(const bf16x8*)(vrow + 9216);
  }

  for (int kt = 0; kt < nkt; kt++) {
    int cur = kt & 1;
    int kv0 = kt * 64;
    asm volatile("s_waitcnt vmcnt(0)" ::: "memory");

#pragma unroll
    for (int j = 0; j < 8; j++) {
      bf16x4 w;
      w[0] = vr0[j]; w[1] = vr1[j]; w[2] = vr2[j]; w[3] = vr3[j];
      *(bf16x4*)&Vt[cur][dc + j][kvw] = w;
    }

    asm volatile("s_waitcnt lgkmcnt(0)" ::: "memory");
    __builtin_amdgcn_sched_barrier(0);
    __builtin_amdgcn_s_barrier();
    __builtin_amdgcn_sched_barrier(0);

    if (kt + 1 < nkt) {
      int kv1 = kv0 + 64;
      bf16* kdst = &Kl[cur ^ 1][0];
#pragma unroll
      for (int r = 0; r < 4; r++) {
        int ci = r * 256 + tid;
        int row = ci >> 4;
        int sl = (ci & 15) ^ (row & 15);
        glds16(kgbase + (size_t)(kv1 + row) * 3072 + sl * 8, kdst + ci * 8);
      }
      const bf16* vrow = vgbase + (size_t)(kv1 + kq4) * 3072 + dc;
      vr0 = *(const bf16x8*)(vrow);
      vr1 = *(const bf16x8*)(vrow + 3072);
      vr2 = *(const bf16x8*)(vrow + 6144);
      vr3 = *(const bf16x8*)(vrow + 9216);
    }

    if (kv0 + kvbase <= qmax) {
      f32x16 s0 = {};
      const char* kb0 = (const char*)&Kl[cur][0] + kvhalf * 8192 + li * 256;
      __builtin_amdgcn_s_setprio(1);
#pragma unroll
      for (int ks = 0; ks < 8; ks++) {
        int off = ((ks * 2 + hi) ^ (li & 15)) << 4;
        bf16x8 kf0 = *(const bf16x8*)(kb0 + off);
        s0 = __builtin_amdgcn_mfma_f32_32x32x16_bf16(kf0, qf[ks], s0, 0, 0, 0);
      }
      __builtin_amdgcn_s_setprio(0);

      if (kv0 + kvbase + 31 > qmin) {
        int base0 = kv0 + kvbase + 4 * hi - qlane;
#pragma unroll
        for (int r = 0; r < 16; r++) {
          int off = (r & 3) + 8 * (r >> 2);
          if (base0 + off > 0) s0[r] = -INFINITY;
        }
      }

      float pm = s0[0];
#pragma unroll
      for (int r = 1; r < 16; r++) pm = fmaxf(pm, s0[r]);
      pm = fmaxf(pm, __shfl_xor(pm, 32));

      if (!__all(pm - mrun <= 62.0f)) {
        float mnew = fmaxf(mrun, pm);
        float alpha = exp2f((mrun - mnew) * C1);
        mrun = mnew;
        lpart *= alpha;
        Tabs[0][wid][li] = alpha;
        asm volatile("s_waitcnt lgkmcnt(0)" ::: "memory");
        f32x4 a0 = *(const f32x4*)&Tabs[0][wid][4 * hi];
        f32x4 a1 = *(const f32x4*)&Tabs[0][wid][4 * hi + 8];
        f32x4 a2 = *(const f32x4*)&Tabs[0][wid][4 * hi + 16];
        f32x4 a3 = *(const f32x4*)&Tabs[0][wid][4 * hi + 24];
#define RESC_RR(rr, av)                                            \
  _Pragma("unroll") for (int i = 0; i < 4; i++) {                  \
    float f = av[i];                                               \
    o0[rr * 4 + i] *= f; o1[rr * 4 + i] *= f;                      \
    o2[rr * 4 + i] *= f; o3[rr * 4 + i] *= f;                      \
  }
        RESC_RR(0, a0) RESC_RR(1, a1) RESC_RR(2, a2) RESC_RR(3, a3)
#undef RESC_RR
      }

      float mC = mrun * C1;
      float rs = 0.f;
#pragma unroll
      for (int r = 0; r < 16; r++) {
        float p = exp2f(fmaf(s0[r], C1, -mC));
        s0[r] = p; rs += p;
      }
      lpart += rs;

      union U4 { unsigned int u[4]; bf16x8 v; };
      U4 pa0, pa1;
      {
        unsigned int e0 = cvtpk(s0[0], s0[1]), e1 = cvtpk(s0[2], s0[3]);
        unsigned int e2 = cvtpk(s0[4], s0[5]), e3 = cvtpk(s0[6], s0[7]);
        unsigned int e4 = cvtpk(s0[8], s0[9]), e5 = cvtpk(s0[10], s0[11]);
        unsigned int e6 = cvtpk(s0[12], s0[13]), e7 = cvtpk(s0[14], s0[15]);
        unsigned int t0 = __shfl_xor(e0, 32), t1 = __shfl_xor(e1, 32);
        unsigned int t2 = __shfl_xor(e2, 32), t3 = __shfl_xor(e3, 32);
        unsigned int t4 = __shfl_xor(e4, 32), t5 = __shfl_xor(e5, 32);
        unsigned int t6 = __shfl_xor(e6, 32), t7 = __shfl_xor(e7, 32);
        pa0.u[0] = hi ? t2 : e0;  pa0.u[1] = hi ? t3 : e1;
        pa0.u[2] = hi ? e2 : t0;  pa0.u[3] = hi ? e3 : t1;
        pa1.u[0] = hi ? t6 : e4;  pa1.u[1] = hi ? t7 : e5;
        pa1.u[2] = hi ? e6 : t4;  pa1.u[3] = hi ? e7 : t5;
      }

      __builtin_amdgcn_s_setprio(1);
#define PV_DB(OACC, DB)                                                      \
  {                                                                          \
    int d = DB * 32 + li;                                                    \
    int xv = ((d >> 3) & 7) << 3;                                            \
    bf16x8 vb0 = *(const bf16x8*)&Vt[cur][d][(kvbase + hi * 8) ^ xv];        \
    bf16x8 vb1 = *(const bf16x8*)&Vt[cur][d][(kvbase + 16 + hi * 8) ^ xv];   \
    OACC = __builtin_amdgcn_mfma_f32_32x32x16_bf16(pa0.v, vb0, OACC, 0, 0, 0); \
    OACC = __builtin_amdgcn_mfma_f32_32x32x16_bf16(pa1.v, vb1, OACC, 0, 0, 0); \
  }
      PV_DB(o0, 0) PV_DB(o1, 1) PV_DB(o2, 2) PV_DB(o3, 3)
#undef PV_DB
      __builtin_amdgcn_s_setprio(0);
    }
  }

  // ---- epilogue: flash-merge kv-half pairs (w, w^2), then store ----
  lpart += __shfl_xor(lpart, 32);
  Tabs[0][wid][li] = mrun;   // M
  Tabs[1][wid][li] = lpart;  // L
  asm volatile("s_waitcnt lgkmcnt(0)" ::: "memory");
  __builtin_amdgcn_s_barrier();
  int peer = wid ^ 2;
  float mP = Tabs[0][peer][li], lP = Tabs[1][peer][li];
  float mS = fmaxf(mrun, mP);
  float fMe = exp2f((mrun - mS) * C1);
  float fPe = exp2f((mP - mS) * C1);
  float lTot = lpart * fMe + lP * fPe;
  Tabs[2][wid][li] = fMe;          // F (own factor)
  Tabs[3][wid][li] = 1.f / lTot;   // I (same for both waves of the pair)
  asm volatile("s_waitcnt lgkmcnt(0)" ::: "memory");
  __builtin_amdgcn_s_barrier();
  f32x4 Fv0 = *(const f32x4*)&Tabs[2][wid][4 * hi];
  f32x4 Fv1 = *(const f32x4*)&Tabs[2][wid][4 * hi + 8];
  f32x4 Fv2 = *(const f32x4*)&Tabs[2][wid][4 * hi + 16];
  f32x4 Fv3 = *(const f32x4*)&Tabs[2][wid][4 * hi + 24];
  f32x4 Iv0 = *(const f32x4*)&Tabs[3][wid][4 * hi];
  f32x4 Iv1 = *(const f32x4*)&Tabs[3][wid][4 * hi + 8];
  f32x4 Iv2 = *(const f32x4*)&Tabs[3][wid][4 * hi + 16];
  f32x4 Iv3 = *(const f32x4*)&Tabs[3][wid][4 * hi + 24];

  float* X = (float*)&Kl[0][0];  // 2 exchange buffers of 4096 floats (32 KB)
  float* Xb = X + (wid & 1) * 4096;
  if (kvhalf == 1) {
#define XW_RR(OACC, DB, rr, Fv)                                              \
  _Pragma("unroll") for (int i = 0; i < 4; i++)                              \
    Xb[(4 * hi + 8 * rr + i) * 128 + DB * 32 + li] = OACC[rr * 4 + i] * Fv[i];
#define XW_DB(OACC, DB) XW_RR(OACC, DB, 0, Fv0) XW_RR(OACC, DB, 1, Fv1) \
                        XW_RR(OACC, DB, 2, Fv2) XW_RR(OACC, DB, 3, Fv3)
    XW_DB(o0, 0) XW_DB(o1, 1) XW_DB(o2, 2) XW_DB(o3, 3)
#undef XW_DB
#undef XW_RR
  }
  asm volatile("s_waitcnt lgkmcnt(0)" ::: "memory");
  __builtin_amdgcn_s_barrier();
  if (kvhalf == 0) {
#define XR_RR(OACC, DB, rr, Fv)                                              \
  _Pragma("unroll") for (int i = 0; i < 4; i++)                              \
    OACC[rr * 4 + i] = OACC[rr * 4 + i] * Fv[i] +                            \
        Xb[(4 * hi + 8 * rr + i) * 128 + DB * 32 + li];
#define XR_DB(OACC, DB) XR_RR(OACC, DB, 0, Fv0) XR_RR(OACC, DB, 1, Fv1) \
                        XR_RR(OACC, DB, 2, Fv2) XR_RR(OACC, DB, 3, Fv3)
    XR_DB(o0, 0) XR_DB(o1, 1) XR_DB(o2, 2) XR_DB(o3, 3)
#undef XR_DB
#undef XR_RR
    size_t obase = (size_t)(b * SEQT) * 2048 + h * HD;
#define STORE_RR(rr, lv)                                                     \
  _Pragma("unroll") for (int i = 0; i < 4; i++) {                            \
    int q = qmin + 4 * hi + 8 * rr + i;                                      \
    size_t rowb = obase + (size_t)q * 2048 + li;                             \
    attout[rowb + 0]  = (bf16)(o0[rr * 4 + i] * lv[i]);                      \
    attout[rowb + 32] = (bf16)(o1[rr * 4 + i] * lv[i]);                      \
    attout[rowb + 64] = (bf16)(o2[rr * 4 + i] * lv[i]);                      \
    attout[rowb + 96] = (bf16)(o3[rr * 4 + i] * lv[i]);                      \
  }
    STORE_RR(0, Iv0) STORE_RR(1, Iv1) STORE_RR(2, Iv2) STORE_RR(3, Iv3)
#undef STORE_RR
  }
}

extern "C" void kernel_launch(void* const* d_in, const int* in_sizes, int n_in,
                              void* d_out, int out_size, void* d_ws, size_t ws_size,
                              hipStream_t stream) {
  const float* x    = (const float*)d_in[0];
  const float* fcos = (const float*)d_in[1];
  const float* fsin = (const float*)d_in[2];
  const float* wq   = (const float*)d_in[3];
  const float* wk   = (const float*)d_in[4];
  const float* wv   = (const float*)d_in[5];
  const float* wo   = (const float*)d_in[6];
  float* out = (float*)d_out;

  // ws layout (bytes): [XB/ATT 16.78M][W 12.58M][QKV 25.17M][WOT 8.39M opt]
  char* ws = (char*)d_ws;
  bf16* XB  = (bf16*)ws;                                    // 4096x2048, later attn out
  bf16* W   = (bf16*)(ws + 16777216);                       // 3072x2048 (B^T panel)
  bf16* QKV = (bf16*)(ws + 16777216 + 12582912);            // 4096x3072
  bool bigws = ws_size >= 62914560ull;
  bf16* WOT = bigws ? (bf16*)(ws + 54525952) : W;           // 2048x2048 wo^T

  dim3 tb(32, 8);
  if (bigws) {
    k_transpose4<<<dim3(160, 64), tb, 0, stream>>>(wq, wk, wv, wo, W, WOT);
  } else {
    k_transpose3<<<dim3(96, 64), tb, 0, stream>>>(wq, wk, wv, W);
  }
  k_convert<<<4096, 256, 0, stream>>>(x, XB, 1048576);
  k_gemm8<bf16><<<192, 512, 0, stream>>>(XB, W, QKV, 12, 2048, 3072);
  k_ropek<<<512, 256, 0, stream>>>(QKV, fcos, fsin);
  k_attn<<<1024, 256, 0, stream>>>(QKV, XB, fcos, fsin);
  if (!bigws) {
    k_transpose<<<dim3(64, 64), tb, 0, stream>>>(wo, W, 2048, 2048);
  }
  k_gemm8n<float><<<256, 512, 0, stream>>>(XB, WOT, out, 16, 2048, 2048);
}